// Round 8
// baseline (2123.333 us; speedup 1.0000x reference)
//
#include <hip/hip_runtime.h>
#include <hip/hip_bf16.h>

#define BSZ 2
#define LLEN 2048
#define NHEADS 32
#define HEADDIM 64
#define DSTATE 128
#define DCONV 4
#define DINNER (NHEADS * HEADDIM)                  // 2048
#define DPROJ  (2 * DINNER + 2 * DSTATE + NHEADS)  // 4384
#define Q 64                                       // scan chunk length
#define NCHUNK (LLEN / Q)                          // 32
#define XCW 2304                                   // XC row: [xv 2048 | B 128 | C 128]

typedef float v2f __attribute__((ext_vector_type(2)));

__device__ __forceinline__ float sigm(float x) {
    return __builtin_amdgcn_rcpf(1.0f + __expf(-x));
}

// Robust python-int scalar read (int32 bits or float32 bits).
__device__ __forceinline__ float int_scalar(const int* p) {
    int i = *p;
    if (i >= 0 && i <= 1000000) return (float)i;
    return __int_as_float(i);
}

// ---------------------------------------------------------------------------
// Kernel 1: conv+silu for ALL 2304 conv channels -> XC row [xv|B|C], plus
// dt/dA. One block per (b,l); thread handles 8 x-channels + 1 B/C channel.
// ---------------------------------------------------------------------------
__global__ __launch_bounds__(256) void pre_kernel(
    const float* __restrict__ zx, const float* __restrict__ cw,
    const float* __restrict__ cb, const float* __restrict__ dtb,
    const float* __restrict__ alog, const float* __restrict__ dts,
    const int* __restrict__ mn_p, const int* __restrict__ mx_p,
    float* __restrict__ XC, float2* __restrict__ dtA)
{
    const int bl  = blockIdx.x;            // 0 .. B*L-1
    const int b   = bl / LLEN;
    const int l   = bl % LLEN;
    const int tid = threadIdx.x;

    // ---- x channels: 8 per thread (conv rows 0..2047, zx cols DINNER+c) ----
    {
        const int c8 = tid * 8;
        float acc[8];
        {
            float4 b0 = *(const float4*)(cb + c8);
            float4 b1 = *(const float4*)(cb + c8 + 4);
            acc[0]=b0.x; acc[1]=b0.y; acc[2]=b0.z; acc[3]=b0.w;
            acc[4]=b1.x; acc[5]=b1.y; acc[6]=b1.z; acc[7]=b1.w;
        }
        float4 w[8];
        #pragma unroll
        for (int j = 0; j < 8; j++) w[j] = *(const float4*)(cw + (size_t)(c8 + j) * 4);
        #pragma unroll
        for (int k = 0; k < DCONV; k++) {
            const int lk = l - (DCONV - 1) + k;
            if (lk >= 0) {
                const float* xr = zx + ((size_t)b * LLEN + lk) * DPROJ + DINNER + c8;
                float4 v0 = *(const float4*)xr;
                float4 v1 = *(const float4*)(xr + 4);
                const float tap[8] = {v0.x,v0.y,v0.z,v0.w,v1.x,v1.y,v1.z,v1.w};
                #pragma unroll
                for (int j = 0; j < 8; j++) {
                    const float wk = (k==0) ? w[j].x : (k==1) ? w[j].y : (k==2) ? w[j].z : w[j].w;
                    acc[j] += wk * tap[j];
                }
            }
        }
        float r[8];
        #pragma unroll
        for (int j = 0; j < 8; j++) r[j] = acc[j] * sigm(acc[j]);
        float* xo = XC + (size_t)bl * XCW + c8;
        *(float4*)xo       = make_float4(r[0], r[1], r[2], r[3]);
        *(float4*)(xo + 4) = make_float4(r[4], r[5], r[6], r[7]);
    }

    // ---- B/C channel: conv row 2048+tid, zx col 4096+tid ----
    {
        const int ch = 2048 + tid;
        float a = cb[ch];
        const float4 wv = *(const float4*)(cw + (size_t)ch * 4);
        #pragma unroll
        for (int k = 0; k < DCONV; k++) {
            const int lk = l - (DCONV - 1) + k;
            if (lk >= 0) {
                const float wk = (k==0) ? wv.x : (k==1) ? wv.y : (k==2) ? wv.z : wv.w;
                a += wk * zx[((size_t)b * LLEN + lk) * DPROJ + DINNER + ch];
            }
        }
        XC[(size_t)bl * XCW + ch] = a * sigm(a);
    }

    // ---- dt / dA ----
    if (tid < NHEADS) {
        float raw = zx[(size_t)bl * DPROJ + (DPROJ - NHEADS) + tid];
        float v   = raw * dts[tid] + dtb[tid];
        float sp  = (v > 20.0f) ? v : log1pf(__expf(v));
        float dt  = fminf(fmaxf(sp, int_scalar(mn_p)), int_scalar(mx_p));
        float A   = -__expf(alog[tid]);
        dtA[(size_t)bl * NHEADS + tid] = make_float2(dt, __expf(dt * A));
    }
}

// ---------------------------------------------------------------------------
// Kernel 2: per-chunk inclusive decay cumprod cumA[t] and chunk totals dtot.
// Q=64: each lane owns exactly 1 t.
// ---------------------------------------------------------------------------
__global__ __launch_bounds__(64) void cum_kernel(
    const float2* __restrict__ dtA, float* __restrict__ cumA,
    float* __restrict__ dtot)
{
    const int c = blockIdx.x, h = blockIdx.y, b = blockIdx.z;
    const int lane = threadIdx.x;          // 0..63 == t within chunk
    float s = dtA[((size_t)(b * LLEN + c * Q + lane)) * NHEADS + h].y;
    #pragma unroll
    for (int off = 1; off < 64; off <<= 1) {
        float v = __shfl_up(s, off, 64);
        if (lane >= off) s *= v;
    }
    cumA[((size_t)(b * NHEADS + h) * NCHUNK + c) * Q + lane] = s;
    if (lane == 63) dtot[(size_t)(b * NHEADS + h) * NCHUNK + c] = s;
}

// ---------------------------------------------------------------------------
// Phase A scan: zero-init local chunk scan.
// One block per (b,h,c). Wave: 4 p-slots x 16 n-groups; lane owns 4
// consecutive p and 8 n (round-7 tile: 4x B/C L1 redundancy).
// Q=64 -> 2048 blocks = 8 blocks/CU; launch_bounds(256,8) claims the full
// 8 waves/SIMD (VGPR cap 64; round-7 demand was 60).
// Inner math in packed float2 (v_pk_fma_f32 path, 157 TF fp32 peak).
// SPILL TRIPWIRE: scan WRITE should be ~100 MB (y 33.5 + SA 67);
// >>110 MB means the 64-reg cap spilled -> revert to (256,4)+Q=128.
// ---------------------------------------------------------------------------
__global__ __launch_bounds__(256, 8) void scan_kernel(
    const float* __restrict__ XC, const float2* __restrict__ dtA,
    const float* __restrict__ d_param, float* __restrict__ SA,
    float* __restrict__ out)
{
    const int c    = blockIdx.x;
    const int h    = blockIdx.y;
    const int b    = blockIdx.z;
    const int tid  = threadIdx.x;
    const int wave = tid >> 6;
    const int lane = tid & 63;
    const int ng   = lane & 15;            // n-group (low 4 bits): 16 groups x 8 n
    const int pl   = lane >> 4;            // 0..3
    const int p0   = wave * 16 + pl * 4;   // 4 consecutive p per lane
    const int n0   = ng * 8;
    const int t0   = c * Q;
    const int cx   = h * HEADDIM + p0;
    const float Dh = d_param[h];

    const float*  pB = XC + ((size_t)b * LLEN + t0) * XCW + 2048 + n0;  // C at +128
    const float*  pv = XC + ((size_t)b * LLEN + t0) * XCW + cx;
    const float2* pd = dtA + ((size_t)b * LLEN + t0) * NHEADS + h;
    float*        pw = out + ((size_t)b * LLEN + t0) * DINNER + cx;

    v2f st[4][4];                          // [p][n-pair]
    #pragma unroll
    for (int j = 0; j < 4; j++)
        #pragma unroll
        for (int n = 0; n < 4; n++) st[j][n] = (v2f){0.0f, 0.0f};

    // depth-2 register ring for B,C,x,dtA
    float4 rb[2][2], rc[2][2], rx[2];
    float2 rda[2];
    #pragma unroll
    for (int u = 0; u < 2; u++) {
        const float* r = pB + (size_t)u * XCW;
        rb[u][0] = *(const float4*)(r);
        rb[u][1] = *(const float4*)(r + 4);
        rc[u][0] = *(const float4*)(r + 128);
        rc[u][1] = *(const float4*)(r + 132);
        rx[u]    = *(const float4*)(pv + (size_t)u * XCW);
        rda[u]   = pd[(size_t)u * NHEADS];
    }
    const float*  pn  = pB + 2 * XCW;      // B/C prefetch row (t+2)
    const float*  pxn = pv + 2 * XCW;      // x prefetch row (t+2)
    const float2* pdn = pd + 2 * NHEADS;

    auto step = [&](int u) {
        const float4 b0 = rb[u][0], b1 = rb[u][1];
        const float4 c0 = rc[u][0], c1 = rc[u][1];
        const v2f B2[4] = {{b0.x,b0.y},{b0.z,b0.w},{b1.x,b1.y},{b1.z,b1.w}};
        const v2f C2[4] = {{c0.x,c0.y},{c0.z,c0.w},{c1.x,c1.y},{c1.z,c1.w}};
        const float4 xv = rx[u];
        const float2 da = rda[u];

        // prefetch t+2 into slot u (unconditional; overrun lands in pad rows)
        rb[u][0] = *(const float4*)(pn);
        rb[u][1] = *(const float4*)(pn + 4);
        rc[u][0] = *(const float4*)(pn + 128);
        rc[u][1] = *(const float4*)(pn + 132);
        rx[u]    = *(const float4*)pxn;
        rda[u]   = pdn[0];
        pn += XCW; pxn += XCW; pdn += NHEADS;

        const v2f dA2 = {da.y, da.y};
        const float cf[4] = {da.x * xv.x, da.x * xv.y, da.x * xv.z, da.x * xv.w};
        float acc[4];
        #pragma unroll
        for (int j = 0; j < 4; j++) {
            const v2f cf2 = {cf[j], cf[j]};
            v2f a2 = {0.0f, 0.0f};
            #pragma unroll
            for (int n = 0; n < 4; n++) {
                st[j][n] = dA2 * st[j][n] + cf2 * B2[n];   // packed fma pair
                a2 += st[j][n] * C2[n];                    // packed fma
            }
            acc[j] = a2.x + a2.y;
        }
        // reduce each p-dot over the 16 lanes of this pl-group
        #pragma unroll
        for (int m = 1; m <= 8; m <<= 1) {
            acc[0] += __shfl_xor(acc[0], m, 64);
            acc[1] += __shfl_xor(acc[1], m, 64);
            acc[2] += __shfl_xor(acc[2], m, 64);
            acc[3] += __shfl_xor(acc[3], m, 64);
        }

        if (ng == 0) {
            *(float4*)pw = make_float4(acc[0] + Dh * xv.x,
                                       acc[1] + Dh * xv.y,
                                       acc[2] + Dh * xv.z,
                                       acc[3] + Dh * xv.w);   // ungated y_pre
        }
        pw += DINNER;
    };

    for (int tb = 0; tb < Q; tb += 2) {
        step(0); step(1);
    }

    // store chunk-end local state: SA[p][n], p = p0+j, n = n0..n0+7
    const size_t sb = ((size_t)(b * NHEADS + h) * NCHUNK + c) * (HEADDIM * DSTATE)
                    + (size_t)p0 * DSTATE + n0;
    #pragma unroll
    for (int j = 0; j < 4; j++) {
        *(float4*)(SA + sb + (size_t)j * DSTATE)     =
            make_float4(st[j][0].x, st[j][0].y, st[j][1].x, st[j][1].y);
        *(float4*)(SA + sb + (size_t)j * DSTATE + 4) =
            make_float4(st[j][2].x, st[j][2].y, st[j][3].x, st[j][3].y);
    }
}

// ---------------------------------------------------------------------------
// Phase B: sequential chunk combine per (b,h). SA[c] := state ENTERING chunk c.
// Grid (NHEADS, BSZ, 8): 1 float4 per thread; next-chunk prefetch breaks the
// NCHUNK-deep dependent load chain.
// ---------------------------------------------------------------------------
__global__ __launch_bounds__(256) void combine_kernel(
    const float* __restrict__ init_state, const float* __restrict__ dtot,
    float* __restrict__ SA)
{
    const int h = blockIdx.x, b = blockIdx.y, pg = blockIdx.z;
    const size_t hd = (size_t)(b * NHEADS + h);
    const size_t eb = (size_t)pg * 1024 + (size_t)threadIdx.x * 4;

    float4 r = *(const float4*)(init_state + hd * (HEADDIM * DSTATE) + eb);
    const float* dp = dtot + hd * NCHUNK;

    float4* ps = (float4*)(SA + hd * NCHUNK * (size_t)(HEADDIM * DSTATE) + eb);
    const size_t cstride = (HEADDIM * DSTATE) / 4;   // float4 stride per chunk

    float  d  = dp[0];
    float4 l  = ps[0];
    for (int c = 0; c < NCHUNK; c++) {
        const float  curd = d;
        const float4 curl = l;
        if (c + 1 < NCHUNK) {              // prefetch next chunk
            d = dp[c + 1];
            l = ps[(size_t)(c + 1) * cstride];
        }
        ps[(size_t)c * cstride] = r;       // state entering chunk c
        r.x = curd * r.x + curl.x;
        r.y = curd * r.y + curl.y;
        r.z = curd * r.z + curl.z;
        r.w = curd * r.w + curl.w;
    }
}

// ---------------------------------------------------------------------------
// Phase C: cross-chunk correction as a tiled GEMM + gate epilogue.
//   corr[t,p] = (cumA[t]*C[t,:]) . Sin[p,:]   (K = DSTATE = 128)
//   out[t,p]  = (y_pre[t,p] + corr[t,p]) * silu(z[t,p])
// One block per (b,h,c): 256 threads, 2x8 register tile each (64t x 64p).
// LDS 40 KB -> 4 blocks/CU.
// ---------------------------------------------------------------------------
__global__ __launch_bounds__(256, 4) void gate_kernel(
    const float* __restrict__ zx, const float* __restrict__ XC,
    const float* __restrict__ cumA, const float* __restrict__ SA,
    float* __restrict__ out)
{
    __shared__ float sT[DSTATE][HEADDIM];   // Sin^T [n][p], 32 KB
    __shared__ float sC[32][Q];             // scaled C panel [k][t], 8 KB

    const int c = blockIdx.x, h = blockIdx.y, b = blockIdx.z;
    const int tid = threadIdx.x;
    const int tx = tid & 31;                // t-tile: t = tx*2 + i
    const int ty = tid >> 5;                // p-tile: p = ty*8 + j
    const size_t hd = (size_t)(b * NHEADS + h);
    const size_t row0 = (size_t)b * LLEN + c * Q;

    // ---- load Sin^T (transpose SA[p][n] -> sT[n][p]) ----
    {
        const int p  = tid >> 2;
        const int nq = (tid & 3) * 32;
        const float* ps = SA + (hd * NCHUNK + c) * (size_t)(HEADDIM * DSTATE)
                        + (size_t)p * DSTATE + nq;
        #pragma unroll
        for (int i = 0; i < 8; i++) {
            float4 v = *(const float4*)(ps + i * 4);
            const int n = nq + i * 4;
            sT[n][p] = v.x; sT[n+1][p] = v.y; sT[n+2][p] = v.z; sT[n+3][p] = v.w;
        }
    }

    float acc[2][8];
    #pragma unroll
    for (int i = 0; i < 2; i++)
        #pragma unroll
        for (int j = 0; j < 8; j++) acc[i][j] = 0.0f;

    const float* pCbase = XC + row0 * XCW + 2176;           // C columns
    const float* pcm    = cumA + (hd * NCHUNK + c) * Q;

    for (int kp = 0; kp < 4; kp++) {                        // 4 K-panels of 32
        __syncthreads();
        {   // stage cumA-scaled C panel, coalesced in groups of 8 lanes
            const int k4 = (tid & 7) * 4;
            #pragma unroll
            for (int rep = 0; rep < Q / 32; rep++) {
                const int t = (tid >> 3) + rep * 32;
                float4 v = *(const float4*)(pCbase + (size_t)t * XCW + kp * 32 + k4);
                const float cm = pcm[t];
                sC[k4+0][t] = v.x * cm;
                sC[k4+1][t] = v.y * cm;
                sC[k4+2][t] = v.z * cm;
                sC[k4+3][t] = v.w * cm;
            }
        }
        __syncthreads();

        // software-pipelined inner product over the 32 k of this panel
        float avA[2], bvA[8], avB[2], bvB[8];
        *(float2*)&avA[0] = *(const float2*)&sC[0][tx*2];
        *(float4*)&bvA[0] = *(const float4*)&sT[kp*32][ty*8];
        *(float4*)&bvA[4] = *(const float4*)&sT[kp*32][ty*8+4];
        for (int k = 0; k < 32; k += 2) {
            *(float2*)&avB[0] = *(const float2*)&sC[k+1][tx*2];
            *(float4*)&bvB[0] = *(const float4*)&sT[kp*32+k+1][ty*8];
            *(float4*)&bvB[4] = *(const float4*)&sT[kp*32+k+1][ty*8+4];
            #pragma unroll
            for (int i = 0; i < 2; i++)
                #pragma unroll
                for (int j = 0; j < 8; j++) acc[i][j] += avA[i] * bvA[j];
            if (k + 2 < 32) {
                *(float2*)&avA[0] = *(const float2*)&sC[k+2][tx*2];
                *(float4*)&bvA[0] = *(const float4*)&sT[kp*32+k+2][ty*8];
                *(float4*)&bvA[4] = *(const float4*)&sT[kp*32+k+2][ty*8+4];
            }
            #pragma unroll
            for (int i = 0; i < 2; i++)
                #pragma unroll
                for (int j = 0; j < 8; j++) acc[i][j] += avB[i] * bvB[j];
        }
    }

    // ---- epilogue: out = (y_pre + corr) * silu(z) ----
    #pragma unroll
    for (int i = 0; i < 2; i++) {
        const int t = tx * 2 + i;
        float* po = out + (row0 + t) * (size_t)DINNER + h * HEADDIM + ty * 8;
        const float* pz = zx + (row0 + t) * (size_t)DPROJ + h * HEADDIM + ty * 8;
        float4 y0 = *(const float4*)po;
        float4 y1 = *(const float4*)(po + 4);
        float4 z0 = *(const float4*)pz;
        float4 z1 = *(const float4*)(pz + 4);
        const float yv[8] = {y0.x,y0.y,y0.z,y0.w,y1.x,y1.y,y1.z,y1.w};
        const float zv[8] = {z0.x,z0.y,z0.z,z0.w,z1.x,z1.y,z1.z,z1.w};
        float r[8];
        #pragma unroll
        for (int j = 0; j < 8; j++) {
            const float zg = zv[j] * sigm(zv[j]);
            r[j] = (yv[j] + acc[i][j]) * zg;
        }
        *(float4*)po       = make_float4(r[0], r[1], r[2], r[3]);
        *(float4*)(po + 4) = make_float4(r[4], r[5], r[6], r[7]);
    }
}

// ---------------------------------------------------------------------------
extern "C" void kernel_launch(void* const* d_in, const int* in_sizes, int n_in,
                              void* d_out, int out_size, void* d_ws, size_t ws_size,
                              hipStream_t stream) {
    const float* zxbcdt   = (const float*)d_in[0];
    const float* conv_w   = (const float*)d_in[1];
    const float* conv_b   = (const float*)d_in[2];
    const float* dt_bias  = (const float*)d_in[3];
    const float* a_log    = (const float*)d_in[4];
    const float* d_param  = (const float*)d_in[5];
    const float* dt_scale = (const float*)d_in[6];
    const float* init_st  = (const float*)d_in[7];
    const int* dt_min_p   = (const int*)d_in[11];
    const int* dt_max_p   = (const int*)d_in[12];
    float* out = (float*)d_out;

    // workspace: XC (pad +4) 37.8 + dtA 1 + SA 67.1 + cumA 0.5 MiB ~= 106.5 MiB
    char* ws = (char*)d_ws;
    const size_t n_bl = (size_t)BSZ * LLEN;                           // 4096
    float*  XC  = (float*)ws;  ws += (n_bl + 4) * XCW * sizeof(float);
    float2* dtA = (float2*)ws; ws += n_bl * NHEADS * sizeof(float2);
    float*  SA  = (float*)ws;
    ws += (size_t)BSZ * NHEADS * NCHUNK * HEADDIM * DSTATE * sizeof(float);
    float*  dtot = (float*)ws; ws += (size_t)BSZ * NHEADS * NCHUNK * sizeof(float);
    float*  cumA = (float*)ws;
    ws += (size_t)BSZ * NHEADS * LLEN * sizeof(float);

    pre_kernel<<<dim3((unsigned)n_bl), 256, 0, stream>>>(
        zxbcdt, conv_w, conv_b, dt_bias, a_log, dt_scale,
        dt_min_p, dt_max_p, XC, dtA);

    cum_kernel<<<dim3(NCHUNK, NHEADS, BSZ), 64, 0, stream>>>(dtA, cumA, dtot);

    scan_kernel<<<dim3(NCHUNK, NHEADS, BSZ), 256, 0, stream>>>(
        XC, dtA, d_param, SA, out);

    combine_kernel<<<dim3(NHEADS, BSZ, 8), 256, 0, stream>>>(init_st, dtot, SA);

    gate_kernel<<<dim3(NCHUNK, NHEADS, BSZ), 256, 0, stream>>>(
        zxbcdt, XC, cumA, SA, out);
}

// Round 9
// 960.094 us; speedup vs baseline: 2.2116x; 2.2116x over previous
//
#include <hip/hip_runtime.h>
#include <hip/hip_bf16.h>

#define BSZ 2
#define LLEN 2048
#define NHEADS 32
#define HEADDIM 64
#define DSTATE 128
#define DCONV 4
#define DINNER (NHEADS * HEADDIM)                  // 2048
#define DPROJ  (2 * DINNER + 2 * DSTATE + NHEADS)  // 4384
#define Q 64                                       // scan chunk length
#define NCHUNK (LLEN / Q)                          // 32
#define XCW 2304                                   // XC row: [xv 2048 | B 128 | C 128]

__device__ __forceinline__ float sigm(float x) {
    return __builtin_amdgcn_rcpf(1.0f + __expf(-x));
}

// Robust python-int scalar read (int32 bits or float32 bits).
__device__ __forceinline__ float int_scalar(const int* p) {
    int i = *p;
    if (i >= 0 && i <= 1000000) return (float)i;
    return __int_as_float(i);
}

// ---------------------------------------------------------------------------
// Kernel 1: conv+silu for ALL 2304 conv channels -> XC row [xv|B|C], plus
// dt/dA. One block per (b,l); thread handles 8 x-channels + 1 B/C channel.
// ---------------------------------------------------------------------------
__global__ __launch_bounds__(256) void pre_kernel(
    const float* __restrict__ zx, const float* __restrict__ cw,
    const float* __restrict__ cb, const float* __restrict__ dtb,
    const float* __restrict__ alog, const float* __restrict__ dts,
    const int* __restrict__ mn_p, const int* __restrict__ mx_p,
    float* __restrict__ XC, float2* __restrict__ dtA)
{
    const int bl  = blockIdx.x;            // 0 .. B*L-1
    const int b   = bl / LLEN;
    const int l   = bl % LLEN;
    const int tid = threadIdx.x;

    // ---- x channels: 8 per thread (conv rows 0..2047, zx cols DINNER+c) ----
    {
        const int c8 = tid * 8;
        float acc[8];
        {
            float4 b0 = *(const float4*)(cb + c8);
            float4 b1 = *(const float4*)(cb + c8 + 4);
            acc[0]=b0.x; acc[1]=b0.y; acc[2]=b0.z; acc[3]=b0.w;
            acc[4]=b1.x; acc[5]=b1.y; acc[6]=b1.z; acc[7]=b1.w;
        }
        float4 w[8];
        #pragma unroll
        for (int j = 0; j < 8; j++) w[j] = *(const float4*)(cw + (size_t)(c8 + j) * 4);
        #pragma unroll
        for (int k = 0; k < DCONV; k++) {
            const int lk = l - (DCONV - 1) + k;
            if (lk >= 0) {
                const float* xr = zx + ((size_t)b * LLEN + lk) * DPROJ + DINNER + c8;
                float4 v0 = *(const float4*)xr;
                float4 v1 = *(const float4*)(xr + 4);
                const float tap[8] = {v0.x,v0.y,v0.z,v0.w,v1.x,v1.y,v1.z,v1.w};
                #pragma unroll
                for (int j = 0; j < 8; j++) {
                    const float wk = (k==0) ? w[j].x : (k==1) ? w[j].y : (k==2) ? w[j].z : w[j].w;
                    acc[j] += wk * tap[j];
                }
            }
        }
        float r[8];
        #pragma unroll
        for (int j = 0; j < 8; j++) r[j] = acc[j] * sigm(acc[j]);
        float* xo = XC + (size_t)bl * XCW + c8;
        *(float4*)xo       = make_float4(r[0], r[1], r[2], r[3]);
        *(float4*)(xo + 4) = make_float4(r[4], r[5], r[6], r[7]);
    }

    // ---- B/C channel: conv row 2048+tid, zx col 4096+tid ----
    {
        const int ch = 2048 + tid;
        float a = cb[ch];
        const float4 wv = *(const float4*)(cw + (size_t)ch * 4);
        #pragma unroll
        for (int k = 0; k < DCONV; k++) {
            const int lk = l - (DCONV - 1) + k;
            if (lk >= 0) {
                const float wk = (k==0) ? wv.x : (k==1) ? wv.y : (k==2) ? wv.z : wv.w;
                a += wk * zx[((size_t)b * LLEN + lk) * DPROJ + DINNER + ch];
            }
        }
        XC[(size_t)bl * XCW + ch] = a * sigm(a);
    }

    // ---- dt / dA ----
    if (tid < NHEADS) {
        float raw = zx[(size_t)bl * DPROJ + (DPROJ - NHEADS) + tid];
        float v   = raw * dts[tid] + dtb[tid];
        float sp  = (v > 20.0f) ? v : log1pf(__expf(v));
        float dt  = fminf(fmaxf(sp, int_scalar(mn_p)), int_scalar(mx_p));
        float A   = -__expf(alog[tid]);
        dtA[(size_t)bl * NHEADS + tid] = make_float2(dt, __expf(dt * A));
    }
}

// ---------------------------------------------------------------------------
// Kernel 2: per-chunk inclusive decay cumprod cumA[t] and chunk totals dtot.
// Q=64: each lane owns exactly 1 t.
// ---------------------------------------------------------------------------
__global__ __launch_bounds__(64) void cum_kernel(
    const float2* __restrict__ dtA, float* __restrict__ cumA,
    float* __restrict__ dtot)
{
    const int c = blockIdx.x, h = blockIdx.y, b = blockIdx.z;
    const int lane = threadIdx.x;          // 0..63 == t within chunk
    float s = dtA[((size_t)(b * LLEN + c * Q + lane)) * NHEADS + h].y;
    #pragma unroll
    for (int off = 1; off < 64; off <<= 1) {
        float v = __shfl_up(s, off, 64);
        if (lane >= off) s *= v;
    }
    cumA[((size_t)(b * NHEADS + h) * NCHUNK + c) * Q + lane] = s;
    if (lane == 63) dtot[(size_t)(b * NHEADS + h) * NCHUNK + c] = s;
}

// ---------------------------------------------------------------------------
// Phase A scan: zero-init local chunk scan.
// One block per (b,h,c). Wave: 4 p-slots x 16 n-groups; lane owns 4
// consecutive p and 8 n (round-7 tile; SCALAR math, known 60-VGPR/spill-free).
// Q=64 -> 2048 blocks; __launch_bounds__(256,6): VGPR cap ~85 >> 60 demand
// (NO SPILL) while letting 6 blocks/CU reside (~50% occ vs round-7's 33%).
// HARD LESSON (rounds 4 & 8): caps of 128 with depth-4 ring, or 64 with
// anything, spill catastrophically (4-9 GB scratch). Keep cap >= demand+25.
// SPILL TRIPWIRE: scan WRITE ~100 MB (y 33.5 + SA 67); >>110 MB -> spilled.
// ---------------------------------------------------------------------------
__global__ __launch_bounds__(256, 6) void scan_kernel(
    const float* __restrict__ XC, const float2* __restrict__ dtA,
    const float* __restrict__ d_param, float* __restrict__ SA,
    float* __restrict__ out)
{
    const int c    = blockIdx.x;
    const int h    = blockIdx.y;
    const int b    = blockIdx.z;
    const int tid  = threadIdx.x;
    const int wave = tid >> 6;
    const int lane = tid & 63;
    const int ng   = lane & 15;            // n-group (low 4 bits): 16 groups x 8 n
    const int pl   = lane >> 4;            // 0..3
    const int p0   = wave * 16 + pl * 4;   // 4 consecutive p per lane
    const int n0   = ng * 8;
    const int t0   = c * Q;
    const int cx   = h * HEADDIM + p0;
    const float Dh = d_param[h];

    const float*  pB = XC + ((size_t)b * LLEN + t0) * XCW + 2048 + n0;  // C at +128
    const float*  pv = XC + ((size_t)b * LLEN + t0) * XCW + cx;
    const float2* pd = dtA + ((size_t)b * LLEN + t0) * NHEADS + h;
    float*        pw = out + ((size_t)b * LLEN + t0) * DINNER + cx;

    float st[4][8];
    #pragma unroll
    for (int j = 0; j < 4; j++)
        #pragma unroll
        for (int n = 0; n < 8; n++) st[j][n] = 0.0f;

    // depth-2 register ring for B,C,x,dtA
    float4 rb[2][2], rc[2][2], rx[2];
    float2 rda[2];
    #pragma unroll
    for (int u = 0; u < 2; u++) {
        const float* r = pB + (size_t)u * XCW;
        rb[u][0] = *(const float4*)(r);
        rb[u][1] = *(const float4*)(r + 4);
        rc[u][0] = *(const float4*)(r + 128);
        rc[u][1] = *(const float4*)(r + 132);
        rx[u]    = *(const float4*)(pv + (size_t)u * XCW);
        rda[u]   = pd[(size_t)u * NHEADS];
    }
    const float*  pn  = pB + 2 * XCW;      // B/C prefetch row (t+2)
    const float*  pxn = pv + 2 * XCW;      // x prefetch row (t+2)
    const float2* pdn = pd + 2 * NHEADS;

    auto step = [&](int u) {
        const float Bv[8] = {rb[u][0].x, rb[u][0].y, rb[u][0].z, rb[u][0].w,
                             rb[u][1].x, rb[u][1].y, rb[u][1].z, rb[u][1].w};
        const float Cv[8] = {rc[u][0].x, rc[u][0].y, rc[u][0].z, rc[u][0].w,
                             rc[u][1].x, rc[u][1].y, rc[u][1].z, rc[u][1].w};
        const float4 xv = rx[u];
        const float2 da = rda[u];

        // prefetch t+2 into slot u (unconditional; overrun lands in pad rows)
        rb[u][0] = *(const float4*)(pn);
        rb[u][1] = *(const float4*)(pn + 4);
        rc[u][0] = *(const float4*)(pn + 128);
        rc[u][1] = *(const float4*)(pn + 132);
        rx[u]    = *(const float4*)pxn;
        rda[u]   = pdn[0];
        pn += XCW; pxn += XCW; pdn += NHEADS;

        const float dAv = da.y;
        const float cf[4] = {da.x * xv.x, da.x * xv.y, da.x * xv.z, da.x * xv.w};
        float acc[4] = {0.f, 0.f, 0.f, 0.f};
        #pragma unroll
        for (int n = 0; n < 8; n++) {
            #pragma unroll
            for (int j = 0; j < 4; j++) {
                st[j][n] = dAv * st[j][n] + cf[j] * Bv[n];
                acc[j]  += st[j][n] * Cv[n];
            }
        }
        // reduce each p-dot over the 16 lanes of this pl-group
        #pragma unroll
        for (int m = 1; m <= 8; m <<= 1) {
            acc[0] += __shfl_xor(acc[0], m, 64);
            acc[1] += __shfl_xor(acc[1], m, 64);
            acc[2] += __shfl_xor(acc[2], m, 64);
            acc[3] += __shfl_xor(acc[3], m, 64);
        }

        if (ng == 0) {
            *(float4*)pw = make_float4(acc[0] + Dh * xv.x,
                                       acc[1] + Dh * xv.y,
                                       acc[2] + Dh * xv.z,
                                       acc[3] + Dh * xv.w);   // ungated y_pre
        }
        pw += DINNER;
    };

    for (int tb = 0; tb < Q; tb += 2) {
        step(0); step(1);
    }

    // store chunk-end local state: SA[p][n], p = p0+j, n = n0..n0+7
    const size_t sb = ((size_t)(b * NHEADS + h) * NCHUNK + c) * (HEADDIM * DSTATE)
                    + (size_t)p0 * DSTATE + n0;
    #pragma unroll
    for (int j = 0; j < 4; j++) {
        *(float4*)(SA + sb + (size_t)j * DSTATE)     =
            make_float4(st[j][0], st[j][1], st[j][2], st[j][3]);
        *(float4*)(SA + sb + (size_t)j * DSTATE + 4) =
            make_float4(st[j][4], st[j][5], st[j][6], st[j][7]);
    }
}

// ---------------------------------------------------------------------------
// Phase B: sequential chunk combine per (b,h). SA[c] := state ENTERING chunk c.
// Grid (NHEADS, BSZ, 8): 1 float4 per thread; next-chunk prefetch breaks the
// NCHUNK-deep dependent load chain.
// ---------------------------------------------------------------------------
__global__ __launch_bounds__(256) void combine_kernel(
    const float* __restrict__ init_state, const float* __restrict__ dtot,
    float* __restrict__ SA)
{
    const int h = blockIdx.x, b = blockIdx.y, pg = blockIdx.z;
    const size_t hd = (size_t)(b * NHEADS + h);
    const size_t eb = (size_t)pg * 1024 + (size_t)threadIdx.x * 4;

    float4 r = *(const float4*)(init_state + hd * (HEADDIM * DSTATE) + eb);
    const float* dp = dtot + hd * NCHUNK;

    float4* ps = (float4*)(SA + hd * NCHUNK * (size_t)(HEADDIM * DSTATE) + eb);
    const size_t cstride = (HEADDIM * DSTATE) / 4;   // float4 stride per chunk

    float  d  = dp[0];
    float4 l  = ps[0];
    for (int c = 0; c < NCHUNK; c++) {
        const float  curd = d;
        const float4 curl = l;
        if (c + 1 < NCHUNK) {              // prefetch next chunk
            d = dp[c + 1];
            l = ps[(size_t)(c + 1) * cstride];
        }
        ps[(size_t)c * cstride] = r;       // state entering chunk c
        r.x = curd * r.x + curl.x;
        r.y = curd * r.y + curl.y;
        r.z = curd * r.z + curl.z;
        r.w = curd * r.w + curl.w;
    }
}

// ---------------------------------------------------------------------------
// Phase C: cross-chunk correction as a tiled GEMM + gate epilogue.
//   corr[t,p] = (cumA[t]*C[t,:]) . Sin[p,:]   (K = DSTATE = 128)
//   out[t,p]  = (y_pre[t,p] + corr[t,p]) * silu(z[t,p])
// One block per (b,h,c): 256 threads, 2x8 register tile each (64t x 64p).
// LDS 40 KB -> 4 blocks/CU.
// ---------------------------------------------------------------------------
__global__ __launch_bounds__(256, 4) void gate_kernel(
    const float* __restrict__ zx, const float* __restrict__ XC,
    const float* __restrict__ cumA, const float* __restrict__ SA,
    float* __restrict__ out)
{
    __shared__ float sT[DSTATE][HEADDIM];   // Sin^T [n][p], 32 KB
    __shared__ float sC[32][Q];             // scaled C panel [k][t], 8 KB

    const int c = blockIdx.x, h = blockIdx.y, b = blockIdx.z;
    const int tid = threadIdx.x;
    const int tx = tid & 31;                // t-tile: t = tx*2 + i
    const int ty = tid >> 5;                // p-tile: p = ty*8 + j
    const size_t hd = (size_t)(b * NHEADS + h);
    const size_t row0 = (size_t)b * LLEN + c * Q;

    // ---- load Sin^T (transpose SA[p][n] -> sT[n][p]) ----
    {
        const int p  = tid >> 2;
        const int nq = (tid & 3) * 32;
        const float* ps = SA + (hd * NCHUNK + c) * (size_t)(HEADDIM * DSTATE)
                        + (size_t)p * DSTATE + nq;
        #pragma unroll
        for (int i = 0; i < 8; i++) {
            float4 v = *(const float4*)(ps + i * 4);
            const int n = nq + i * 4;
            sT[n][p] = v.x; sT[n+1][p] = v.y; sT[n+2][p] = v.z; sT[n+3][p] = v.w;
        }
    }

    float acc[2][8];
    #pragma unroll
    for (int i = 0; i < 2; i++)
        #pragma unroll
        for (int j = 0; j < 8; j++) acc[i][j] = 0.0f;

    const float* pCbase = XC + row0 * XCW + 2176;           // C columns
    const float* pcm    = cumA + (hd * NCHUNK + c) * Q;

    for (int kp = 0; kp < 4; kp++) {                        // 4 K-panels of 32
        __syncthreads();
        {   // stage cumA-scaled C panel, coalesced in groups of 8 lanes
            const int k4 = (tid & 7) * 4;
            #pragma unroll
            for (int rep = 0; rep < Q / 32; rep++) {
                const int t = (tid >> 3) + rep * 32;
                float4 v = *(const float4*)(pCbase + (size_t)t * XCW + kp * 32 + k4);
                const float cm = pcm[t];
                sC[k4+0][t] = v.x * cm;
                sC[k4+1][t] = v.y * cm;
                sC[k4+2][t] = v.z * cm;
                sC[k4+3][t] = v.w * cm;
            }
        }
        __syncthreads();

        // software-pipelined inner product over the 32 k of this panel
        float avA[2], bvA[8], avB[2], bvB[8];
        *(float2*)&avA[0] = *(const float2*)&sC[0][tx*2];
        *(float4*)&bvA[0] = *(const float4*)&sT[kp*32][ty*8];
        *(float4*)&bvA[4] = *(const float4*)&sT[kp*32][ty*8+4];
        for (int k = 0; k < 32; k += 2) {
            *(float2*)&avB[0] = *(const float2*)&sC[k+1][tx*2];
            *(float4*)&bvB[0] = *(const float4*)&sT[kp*32+k+1][ty*8];
            *(float4*)&bvB[4] = *(const float4*)&sT[kp*32+k+1][ty*8+4];
            #pragma unroll
            for (int i = 0; i < 2; i++)
                #pragma unroll
                for (int j = 0; j < 8; j++) acc[i][j] += avA[i] * bvA[j];
            if (k + 2 < 32) {
                *(float2*)&avA[0] = *(const float2*)&sC[k+2][tx*2];
                *(float4*)&bvA[0] = *(const float4*)&sT[kp*32+k+2][ty*8];
                *(float4*)&bvA[4] = *(const float4*)&sT[kp*32+k+2][ty*8+4];
            }
            #pragma unroll
            for (int i = 0; i < 2; i++)
                #pragma unroll
                for (int j = 0; j < 8; j++) acc[i][j] += avB[i] * bvB[j];
        }
    }

    // ---- epilogue: out = (y_pre + corr) * silu(z) ----
    #pragma unroll
    for (int i = 0; i < 2; i++) {
        const int t = tx * 2 + i;
        float* po = out + (row0 + t) * (size_t)DINNER + h * HEADDIM + ty * 8;
        const float* pz = zx + (row0 + t) * (size_t)DPROJ + h * HEADDIM + ty * 8;
        float4 y0 = *(const float4*)po;
        float4 y1 = *(const float4*)(po + 4);
        float4 z0 = *(const float4*)pz;
        float4 z1 = *(const float4*)(pz + 4);
        const float yv[8] = {y0.x,y0.y,y0.z,y0.w,y1.x,y1.y,y1.z,y1.w};
        const float zv[8] = {z0.x,z0.y,z0.z,z0.w,z1.x,z1.y,z1.z,z1.w};
        float r[8];
        #pragma unroll
        for (int j = 0; j < 8; j++) {
            const float zg = zv[j] * sigm(zv[j]);
            r[j] = (yv[j] + acc[i][j]) * zg;
        }
        *(float4*)po       = make_float4(r[0], r[1], r[2], r[3]);
        *(float4*)(po + 4) = make_float4(r[4], r[5], r[6], r[7]);
    }
}

// ---------------------------------------------------------------------------
extern "C" void kernel_launch(void* const* d_in, const int* in_sizes, int n_in,
                              void* d_out, int out_size, void* d_ws, size_t ws_size,
                              hipStream_t stream) {
    const float* zxbcdt   = (const float*)d_in[0];
    const float* conv_w   = (const float*)d_in[1];
    const float* conv_b   = (const float*)d_in[2];
    const float* dt_bias  = (const float*)d_in[3];
    const float* a_log    = (const float*)d_in[4];
    const float* d_param  = (const float*)d_in[5];
    const float* dt_scale = (const float*)d_in[6];
    const float* init_st  = (const float*)d_in[7];
    const int* dt_min_p   = (const int*)d_in[11];
    const int* dt_max_p   = (const int*)d_in[12];
    float* out = (float*)d_out;

    // workspace: XC (pad +4) 37.8 + dtA 1 + SA 67.1 + cumA 0.5 MiB ~= 106.5 MiB
    char* ws = (char*)d_ws;
    const size_t n_bl = (size_t)BSZ * LLEN;                           // 4096
    float*  XC  = (float*)ws;  ws += (n_bl + 4) * XCW * sizeof(float);
    float2* dtA = (float2*)ws; ws += n_bl * NHEADS * sizeof(float2);
    float*  SA  = (float*)ws;
    ws += (size_t)BSZ * NHEADS * NCHUNK * HEADDIM * DSTATE * sizeof(float);
    float*  dtot = (float*)ws; ws += (size_t)BSZ * NHEADS * NCHUNK * sizeof(float);
    float*  cumA = (float*)ws;
    ws += (size_t)BSZ * NHEADS * LLEN * sizeof(float);

    pre_kernel<<<dim3((unsigned)n_bl), 256, 0, stream>>>(
        zxbcdt, conv_w, conv_b, dt_bias, a_log, dt_scale,
        dt_min_p, dt_max_p, XC, dtA);

    cum_kernel<<<dim3(NCHUNK, NHEADS, BSZ), 64, 0, stream>>>(dtA, cumA, dtot);

    scan_kernel<<<dim3(NCHUNK, NHEADS, BSZ), 256, 0, stream>>>(
        XC, dtA, d_param, SA, out);

    combine_kernel<<<dim3(NHEADS, BSZ, 8), 256, 0, stream>>>(init_st, dtot, SA);

    gate_kernel<<<dim3(NCHUNK, NHEADS, BSZ), 256, 0, stream>>>(
        zxbcdt, XC, cumA, SA, out);
}

// Round 10
// 393.107 us; speedup vs baseline: 5.4014x; 2.4423x over previous
//
#include <hip/hip_runtime.h>
#include <hip/hip_bf16.h>

#define BSZ 2
#define LLEN 2048
#define NHEADS 32
#define HEADDIM 64
#define DSTATE 128
#define DCONV 4
#define DINNER (NHEADS * HEADDIM)                  // 2048
#define DPROJ  (2 * DINNER + 2 * DSTATE + NHEADS)  // 4384
#define Q 64                                       // chunk length (aux granularity)
#define NCHUNK (LLEN / Q)                          // 32
#define XCW 2304                                   // XC row: [xv 2048 | B 128 | C 128]

__device__ __forceinline__ float sigm(float x) {
    return __builtin_amdgcn_rcpf(1.0f + __expf(-x));
}

// Robust python-int scalar read (int32 bits or float32 bits).
__device__ __forceinline__ float int_scalar(const int* p) {
    int i = *p;
    if (i >= 0 && i <= 1000000) return (float)i;
    return __int_as_float(i);
}

// ---------------------------------------------------------------------------
// Kernel 1: conv+silu for ALL 2304 conv channels -> XC row [xv|B|C], plus
// dt/dA. One block per (b,l); thread handles 8 x-channels + 1 B/C channel.
// ---------------------------------------------------------------------------
__global__ __launch_bounds__(256) void pre_kernel(
    const float* __restrict__ zx, const float* __restrict__ cw,
    const float* __restrict__ cb, const float* __restrict__ dtb,
    const float* __restrict__ alog, const float* __restrict__ dts,
    const int* __restrict__ mn_p, const int* __restrict__ mx_p,
    float* __restrict__ XC, float2* __restrict__ dtA)
{
    const int bl  = blockIdx.x;            // 0 .. B*L-1
    const int b   = bl / LLEN;
    const int l   = bl % LLEN;
    const int tid = threadIdx.x;

    // ---- x channels: 8 per thread (conv rows 0..2047, zx cols DINNER+c) ----
    {
        const int c8 = tid * 8;
        float acc[8];
        {
            float4 b0 = *(const float4*)(cb + c8);
            float4 b1 = *(const float4*)(cb + c8 + 4);
            acc[0]=b0.x; acc[1]=b0.y; acc[2]=b0.z; acc[3]=b0.w;
            acc[4]=b1.x; acc[5]=b1.y; acc[6]=b1.z; acc[7]=b1.w;
        }
        float4 w[8];
        #pragma unroll
        for (int j = 0; j < 8; j++) w[j] = *(const float4*)(cw + (size_t)(c8 + j) * 4);
        #pragma unroll
        for (int k = 0; k < DCONV; k++) {
            const int lk = l - (DCONV - 1) + k;
            if (lk >= 0) {
                const float* xr = zx + ((size_t)b * LLEN + lk) * DPROJ + DINNER + c8;
                float4 v0 = *(const float4*)xr;
                float4 v1 = *(const float4*)(xr + 4);
                const float tap[8] = {v0.x,v0.y,v0.z,v0.w,v1.x,v1.y,v1.z,v1.w};
                #pragma unroll
                for (int j = 0; j < 8; j++) {
                    const float wk = (k==0) ? w[j].x : (k==1) ? w[j].y : (k==2) ? w[j].z : w[j].w;
                    acc[j] += wk * tap[j];
                }
            }
        }
        float r[8];
        #pragma unroll
        for (int j = 0; j < 8; j++) r[j] = acc[j] * sigm(acc[j]);
        float* xo = XC + (size_t)bl * XCW + c8;
        *(float4*)xo       = make_float4(r[0], r[1], r[2], r[3]);
        *(float4*)(xo + 4) = make_float4(r[4], r[5], r[6], r[7]);
    }

    // ---- B/C channel: conv row 2048+tid, zx col 4096+tid ----
    {
        const int ch = 2048 + tid;
        float a = cb[ch];
        const float4 wv = *(const float4*)(cw + (size_t)ch * 4);
        #pragma unroll
        for (int k = 0; k < DCONV; k++) {
            const int lk = l - (DCONV - 1) + k;
            if (lk >= 0) {
                const float wk = (k==0) ? wv.x : (k==1) ? wv.y : (k==2) ? wv.z : wv.w;
                a += wk * zx[((size_t)b * LLEN + lk) * DPROJ + DINNER + ch];
            }
        }
        XC[(size_t)bl * XCW + ch] = a * sigm(a);
    }

    // ---- dt / dA ----
    if (tid < NHEADS) {
        float raw = zx[(size_t)bl * DPROJ + (DPROJ - NHEADS) + tid];
        float v   = raw * dts[tid] + dtb[tid];
        float sp  = (v > 20.0f) ? v : log1pf(__expf(v));
        float dt  = fminf(fmaxf(sp, int_scalar(mn_p)), int_scalar(mx_p));
        float A   = -__expf(alog[tid]);
        dtA[(size_t)bl * NHEADS + tid] = make_float2(dt, __expf(dt * A));
    }
}

// ---------------------------------------------------------------------------
// Kernel 2: per-chunk inclusive decay cumprod cumA[t] and chunk totals dtot.
// Q=64: each lane owns exactly 1 t.
// ---------------------------------------------------------------------------
__global__ __launch_bounds__(64) void cum_kernel(
    const float2* __restrict__ dtA, float* __restrict__ cumA,
    float* __restrict__ dtot)
{
    const int c = blockIdx.x, h = blockIdx.y, b = blockIdx.z;
    const int lane = threadIdx.x;          // 0..63 == t within chunk
    float s = dtA[((size_t)(b * LLEN + c * Q + lane)) * NHEADS + h].y;
    #pragma unroll
    for (int off = 1; off < 64; off <<= 1) {
        float v = __shfl_up(s, off, 64);
        if (lane >= off) s *= v;
    }
    cumA[((size_t)(b * NHEADS + h) * NCHUNK + c) * Q + lane] = s;
    if (lane == 63) dtot[(size_t)(b * NHEADS + h) * NCHUNK + c] = s;
}

// ---------------------------------------------------------------------------
// Phase A scan: zero-init local chunk scans, TWO Q=64 chunks per block.
// One block per (b,h,chunk-pair). Wave: 4 p-slots x 16 n-groups; lane owns
// 4 consecutive p and 8 n -- EXACTLY the round-7 body (VGPR=60, spill-free,
// 166 us), just with an SA store + state re-zero at the chunk boundary so
// each Q=64 chunk's scan stays local (combine/gate operate per 64-chunk).
// OCCUPANCY LAW (rounds 4/6/8/9): HW buckets are 8 waves@<=64reg,
// 4@<=128, 2@<=256 -- no 5/6/7-wave option. Any launch_bounds min-waves > 4
// forces the 64-reg bucket and the spill heuristic overshoots (VGPR 32-40,
// GBs of scratch). (256,4) with this <=64-reg body is the proven optimum.
// SPILL TRIPWIRE: scan WRITE ~100 MB (y 33.5 + SA 67); >>110 MB -> spilled.
// ---------------------------------------------------------------------------
__global__ __launch_bounds__(256, 4) void scan_kernel(
    const float* __restrict__ XC, const float2* __restrict__ dtA,
    const float* __restrict__ d_param, float* __restrict__ SA,
    float* __restrict__ out)
{
    const int cp   = blockIdx.x;           // chunk pair: chunks 2cp, 2cp+1
    const int h    = blockIdx.y;
    const int b    = blockIdx.z;
    const int tid  = threadIdx.x;
    const int wave = tid >> 6;
    const int lane = tid & 63;
    const int ng   = lane & 15;            // n-group (low 4 bits): 16 groups x 8 n
    const int pl   = lane >> 4;            // 0..3
    const int p0   = wave * 16 + pl * 4;   // 4 consecutive p per lane
    const int n0   = ng * 8;
    const int t0   = cp * 2 * Q;           // 128 timesteps per block
    const int cx   = h * HEADDIM + p0;
    const float Dh = d_param[h];

    const float*  pB = XC + ((size_t)b * LLEN + t0) * XCW + 2048 + n0;  // C at +128
    const float*  pv = XC + ((size_t)b * LLEN + t0) * XCW + cx;
    const float2* pd = dtA + ((size_t)b * LLEN + t0) * NHEADS + h;
    float*        pw = out + ((size_t)b * LLEN + t0) * DINNER + cx;

    float st[4][8];
    #pragma unroll
    for (int j = 0; j < 4; j++)
        #pragma unroll
        for (int n = 0; n < 8; n++) st[j][n] = 0.0f;

    // depth-2 register ring for B,C,x,dtA
    float4 rb[2][2], rc[2][2], rx[2];
    float2 rda[2];
    #pragma unroll
    for (int u = 0; u < 2; u++) {
        const float* r = pB + (size_t)u * XCW;
        rb[u][0] = *(const float4*)(r);
        rb[u][1] = *(const float4*)(r + 4);
        rc[u][0] = *(const float4*)(r + 128);
        rc[u][1] = *(const float4*)(r + 132);
        rx[u]    = *(const float4*)(pv + (size_t)u * XCW);
        rda[u]   = pd[(size_t)u * NHEADS];
    }
    const float*  pn  = pB + 2 * XCW;      // B/C prefetch row (t+2)
    const float*  pxn = pv + 2 * XCW;      // x prefetch row (t+2)
    const float2* pdn = pd + 2 * NHEADS;

    auto step = [&](int u) {
        const float Bv[8] = {rb[u][0].x, rb[u][0].y, rb[u][0].z, rb[u][0].w,
                             rb[u][1].x, rb[u][1].y, rb[u][1].z, rb[u][1].w};
        const float Cv[8] = {rc[u][0].x, rc[u][0].y, rc[u][0].z, rc[u][0].w,
                             rc[u][1].x, rc[u][1].y, rc[u][1].z, rc[u][1].w};
        const float4 xv = rx[u];
        const float2 da = rda[u];

        // prefetch t+2 into slot u (unconditional; overrun lands in pad rows)
        rb[u][0] = *(const float4*)(pn);
        rb[u][1] = *(const float4*)(pn + 4);
        rc[u][0] = *(const float4*)(pn + 128);
        rc[u][1] = *(const float4*)(pn + 132);
        rx[u]    = *(const float4*)pxn;
        rda[u]   = pdn[0];
        pn += XCW; pxn += XCW; pdn += NHEADS;

        const float dAv = da.y;
        const float cf[4] = {da.x * xv.x, da.x * xv.y, da.x * xv.z, da.x * xv.w};
        float acc[4] = {0.f, 0.f, 0.f, 0.f};
        #pragma unroll
        for (int n = 0; n < 8; n++) {
            #pragma unroll
            for (int j = 0; j < 4; j++) {
                st[j][n] = dAv * st[j][n] + cf[j] * Bv[n];
                acc[j]  += st[j][n] * Cv[n];
            }
        }
        // reduce each p-dot over the 16 lanes of this pl-group
        #pragma unroll
        for (int m = 1; m <= 8; m <<= 1) {
            acc[0] += __shfl_xor(acc[0], m, 64);
            acc[1] += __shfl_xor(acc[1], m, 64);
            acc[2] += __shfl_xor(acc[2], m, 64);
            acc[3] += __shfl_xor(acc[3], m, 64);
        }

        if (ng == 0) {
            *(float4*)pw = make_float4(acc[0] + Dh * xv.x,
                                       acc[1] + Dh * xv.y,
                                       acc[2] + Dh * xv.z,
                                       acc[3] + Dh * xv.w);   // ungated y_pre
        }
        pw += DINNER;
    };

    // store chunk-end local state for chunk cc, then reset state to zero
    auto store_sa = [&](int cc) {
        const size_t sb = ((size_t)(b * NHEADS + h) * NCHUNK + cc) * (HEADDIM * DSTATE)
                        + (size_t)p0 * DSTATE + n0;
        #pragma unroll
        for (int j = 0; j < 4; j++) {
            *(float4*)(SA + sb + (size_t)j * DSTATE)     =
                make_float4(st[j][0], st[j][1], st[j][2], st[j][3]);
            *(float4*)(SA + sb + (size_t)j * DSTATE + 4) =
                make_float4(st[j][4], st[j][5], st[j][6], st[j][7]);
            #pragma unroll
            for (int n = 0; n < 8; n++) st[j][n] = 0.0f;
        }
    };

    for (int tb = 0; tb < Q; tb += 2) { step(0); step(1); }
    store_sa(2 * cp);                       // end of first chunk; st zeroed
    for (int tb = 0; tb < Q; tb += 2) { step(0); step(1); }
    store_sa(2 * cp + 1);                   // end of second chunk
}

// ---------------------------------------------------------------------------
// Phase B: sequential chunk combine per (b,h). SA[c] := state ENTERING chunk c.
// Grid (NHEADS, BSZ, 8): 1 float4 per thread; next-chunk prefetch breaks the
// NCHUNK-deep dependent load chain.
// ---------------------------------------------------------------------------
__global__ __launch_bounds__(256) void combine_kernel(
    const float* __restrict__ init_state, const float* __restrict__ dtot,
    float* __restrict__ SA)
{
    const int h = blockIdx.x, b = blockIdx.y, pg = blockIdx.z;
    const size_t hd = (size_t)(b * NHEADS + h);
    const size_t eb = (size_t)pg * 1024 + (size_t)threadIdx.x * 4;

    float4 r = *(const float4*)(init_state + hd * (HEADDIM * DSTATE) + eb);
    const float* dp = dtot + hd * NCHUNK;

    float4* ps = (float4*)(SA + hd * NCHUNK * (size_t)(HEADDIM * DSTATE) + eb);
    const size_t cstride = (HEADDIM * DSTATE) / 4;   // float4 stride per chunk

    float  d  = dp[0];
    float4 l  = ps[0];
    for (int c = 0; c < NCHUNK; c++) {
        const float  curd = d;
        const float4 curl = l;
        if (c + 1 < NCHUNK) {              // prefetch next chunk
            d = dp[c + 1];
            l = ps[(size_t)(c + 1) * cstride];
        }
        ps[(size_t)c * cstride] = r;       // state entering chunk c
        r.x = curd * r.x + curl.x;
        r.y = curd * r.y + curl.y;
        r.z = curd * r.z + curl.z;
        r.w = curd * r.w + curl.w;
    }
}

// ---------------------------------------------------------------------------
// Phase C: cross-chunk correction as a tiled GEMM + gate epilogue.
//   corr[t,p] = (cumA[t]*C[t,:]) . Sin[p,:]   (K = DSTATE = 128)
//   out[t,p]  = (y_pre[t,p] + corr[t,p]) * silu(z[t,p])
// One block per (b,h,c): 256 threads, 2x8 register tile each (64t x 64p).
// LDS 40 KB -> 4 blocks/CU.
// ---------------------------------------------------------------------------
__global__ __launch_bounds__(256, 4) void gate_kernel(
    const float* __restrict__ zx, const float* __restrict__ XC,
    const float* __restrict__ cumA, const float* __restrict__ SA,
    float* __restrict__ out)
{
    __shared__ float sT[DSTATE][HEADDIM];   // Sin^T [n][p], 32 KB
    __shared__ float sC[32][Q];             // scaled C panel [k][t], 8 KB

    const int c = blockIdx.x, h = blockIdx.y, b = blockIdx.z;
    const int tid = threadIdx.x;
    const int tx = tid & 31;                // t-tile: t = tx*2 + i
    const int ty = tid >> 5;                // p-tile: p = ty*8 + j
    const size_t hd = (size_t)(b * NHEADS + h);
    const size_t row0 = (size_t)b * LLEN + c * Q;

    // ---- load Sin^T (transpose SA[p][n] -> sT[n][p]) ----
    {
        const int p  = tid >> 2;
        const int nq = (tid & 3) * 32;
        const float* ps = SA + (hd * NCHUNK + c) * (size_t)(HEADDIM * DSTATE)
                        + (size_t)p * DSTATE + nq;
        #pragma unroll
        for (int i = 0; i < 8; i++) {
            float4 v = *(const float4*)(ps + i * 4);
            const int n = nq + i * 4;
            sT[n][p] = v.x; sT[n+1][p] = v.y; sT[n+2][p] = v.z; sT[n+3][p] = v.w;
        }
    }

    float acc[2][8];
    #pragma unroll
    for (int i = 0; i < 2; i++)
        #pragma unroll
        for (int j = 0; j < 8; j++) acc[i][j] = 0.0f;

    const float* pCbase = XC + row0 * XCW + 2176;           // C columns
    const float* pcm    = cumA + (hd * NCHUNK + c) * Q;

    for (int kp = 0; kp < 4; kp++) {                        // 4 K-panels of 32
        __syncthreads();
        {   // stage cumA-scaled C panel, coalesced in groups of 8 lanes
            const int k4 = (tid & 7) * 4;
            #pragma unroll
            for (int rep = 0; rep < Q / 32; rep++) {
                const int t = (tid >> 3) + rep * 32;
                float4 v = *(const float4*)(pCbase + (size_t)t * XCW + kp * 32 + k4);
                const float cm = pcm[t];
                sC[k4+0][t] = v.x * cm;
                sC[k4+1][t] = v.y * cm;
                sC[k4+2][t] = v.z * cm;
                sC[k4+3][t] = v.w * cm;
            }
        }
        __syncthreads();

        // software-pipelined inner product over the 32 k of this panel
        float avA[2], bvA[8], avB[2], bvB[8];
        *(float2*)&avA[0] = *(const float2*)&sC[0][tx*2];
        *(float4*)&bvA[0] = *(const float4*)&sT[kp*32][ty*8];
        *(float4*)&bvA[4] = *(const float4*)&sT[kp*32][ty*8+4];
        for (int k = 0; k < 32; k += 2) {
            *(float2*)&avB[0] = *(const float2*)&sC[k+1][tx*2];
            *(float4*)&bvB[0] = *(const float4*)&sT[kp*32+k+1][ty*8];
            *(float4*)&bvB[4] = *(const float4*)&sT[kp*32+k+1][ty*8+4];
            #pragma unroll
            for (int i = 0; i < 2; i++)
                #pragma unroll
                for (int j = 0; j < 8; j++) acc[i][j] += avA[i] * bvA[j];
            if (k + 2 < 32) {
                *(float2*)&avA[0] = *(const float2*)&sC[k+2][tx*2];
                *(float4*)&bvA[0] = *(const float4*)&sT[kp*32+k+2][ty*8];
                *(float4*)&bvA[4] = *(const float4*)&sT[kp*32+k+2][ty*8+4];
            }
            #pragma unroll
            for (int i = 0; i < 2; i++)
                #pragma unroll
                for (int j = 0; j < 8; j++) acc[i][j] += avB[i] * bvB[j];
        }
    }

    // ---- epilogue: out = (y_pre + corr) * silu(z) ----
    #pragma unroll
    for (int i = 0; i < 2; i++) {
        const int t = tx * 2 + i;
        float* po = out + (row0 + t) * (size_t)DINNER + h * HEADDIM + ty * 8;
        const float* pz = zx + (row0 + t) * (size_t)DPROJ + h * HEADDIM + ty * 8;
        float4 y0 = *(const float4*)po;
        float4 y1 = *(const float4*)(po + 4);
        float4 z0 = *(const float4*)pz;
        float4 z1 = *(const float4*)(pz + 4);
        const float yv[8] = {y0.x,y0.y,y0.z,y0.w,y1.x,y1.y,y1.z,y1.w};
        const float zv[8] = {z0.x,z0.y,z0.z,z0.w,z1.x,z1.y,z1.z,z1.w};
        float r[8];
        #pragma unroll
        for (int j = 0; j < 8; j++) {
            const float zg = zv[j] * sigm(zv[j]);
            r[j] = (yv[j] + acc[i][j]) * zg;
        }
        *(float4*)po       = make_float4(r[0], r[1], r[2], r[3]);
        *(float4*)(po + 4) = make_float4(r[4], r[5], r[6], r[7]);
    }
}

// ---------------------------------------------------------------------------
extern "C" void kernel_launch(void* const* d_in, const int* in_sizes, int n_in,
                              void* d_out, int out_size, void* d_ws, size_t ws_size,
                              hipStream_t stream) {
    const float* zxbcdt   = (const float*)d_in[0];
    const float* conv_w   = (const float*)d_in[1];
    const float* conv_b   = (const float*)d_in[2];
    const float* dt_bias  = (const float*)d_in[3];
    const float* a_log    = (const float*)d_in[4];
    const float* d_param  = (const float*)d_in[5];
    const float* dt_scale = (const float*)d_in[6];
    const float* init_st  = (const float*)d_in[7];
    const int* dt_min_p   = (const int*)d_in[11];
    const int* dt_max_p   = (const int*)d_in[12];
    float* out = (float*)d_out;

    // workspace: XC (pad +4) 37.8 + dtA 1 + SA 67.1 + cumA 0.5 MiB ~= 106.5 MiB
    char* ws = (char*)d_ws;
    const size_t n_bl = (size_t)BSZ * LLEN;                           // 4096
    float*  XC  = (float*)ws;  ws += (n_bl + 4) * XCW * sizeof(float);
    float2* dtA = (float2*)ws; ws += n_bl * NHEADS * sizeof(float2);
    float*  SA  = (float*)ws;
    ws += (size_t)BSZ * NHEADS * NCHUNK * HEADDIM * DSTATE * sizeof(float);
    float*  dtot = (float*)ws; ws += (size_t)BSZ * NHEADS * NCHUNK * sizeof(float);
    float*  cumA = (float*)ws;
    ws += (size_t)BSZ * NHEADS * LLEN * sizeof(float);

    pre_kernel<<<dim3((unsigned)n_bl), 256, 0, stream>>>(
        zxbcdt, conv_w, conv_b, dt_bias, a_log, dt_scale,
        dt_min_p, dt_max_p, XC, dtA);

    cum_kernel<<<dim3(NCHUNK, NHEADS, BSZ), 64, 0, stream>>>(dtA, cumA, dtot);

    scan_kernel<<<dim3(NCHUNK / 2, NHEADS, BSZ), 256, 0, stream>>>(
        XC, dtA, d_param, SA, out);

    combine_kernel<<<dim3(NHEADS, BSZ, 8), 256, 0, stream>>>(init_st, dtot, SA);

    gate_kernel<<<dim3(NCHUNK, NHEADS, BSZ), 256, 0, stream>>>(
        zxbcdt, XC, cumA, SA, out);
}